// Round 9
// baseline (255.124 us; speedup 1.0000x reference)
//
#include <hip/hip_runtime.h>

// hardwiredAttention: out[b,i,h] = sum_j w[b,i,j] * h_t[j,b,h]
//   w = m_i*m_j*relu(domain[cog,r]-d) / max(w)
// R9: granularity fix. Evidence R3-R8: any mechanism reading the streams as
// 128B-segments-at-2KB-stride plateaus at ~4-5 B/cyc/CU. So: k_prepack reads
// cog/r/d fully coalesced (2KB/wave contiguous), computes w*m_j -> bf16 in
// MFMA-blocked layout W[b][it][s][row128][k32] + gmax; k_transpose writes
// T[b][s][h][k32]; k_gemm is a pure no-LDS no-barrier GEMM where every load
// is 1KB-contiguous per wave; k_scale applies m_i/gmax.

#define B_   64
#define N_   512
#define H_   128
#define NCOG 72
#define NRB  72

typedef __bf16 bf16x8 __attribute__((ext_vector_type(8)));
typedef float  f32x4  __attribute__((ext_vector_type(4)));

// ---------- h_t[j][b][h] fp32 -> T_blk[b][s][h][k] bf16 (s=j>>5, k=j&31) ----
__global__ __launch_bounds__(256) void k_transpose(const float* __restrict__ ht,
                                                   __bf16* __restrict__ T) {
    __shared__ __bf16 tile[32][136];
    const int jt = blockIdx.x * 32;     // j-tile == slab s = blockIdx.x
    const int b  = blockIdx.y;
    const int t  = threadIdx.x;
    {   // load 32 j-rows x 128 h, coalesced on h
        const int jj = t >> 3;
        const int h0 = (t & 7) << 4;
        const float* src = ht + ((size_t)(jt + jj) * B_ + b) * H_ + h0;
        float4 v0 = *(const float4*)(src + 0);
        float4 v1 = *(const float4*)(src + 4);
        float4 v2 = *(const float4*)(src + 8);
        float4 v3 = *(const float4*)(src + 12);
        __bf16* dst = &tile[jj][h0];
        dst[0]=(__bf16)v0.x; dst[1]=(__bf16)v0.y; dst[2]=(__bf16)v0.z; dst[3]=(__bf16)v0.w;
        dst[4]=(__bf16)v1.x; dst[5]=(__bf16)v1.y; dst[6]=(__bf16)v1.z; dst[7]=(__bf16)v1.w;
        dst[8]=(__bf16)v2.x; dst[9]=(__bf16)v2.y; dst[10]=(__bf16)v2.z; dst[11]=(__bf16)v2.w;
        dst[12]=(__bf16)v3.x; dst[13]=(__bf16)v3.y; dst[14]=(__bf16)v3.z; dst[15]=(__bf16)v3.w;
    }
    __syncthreads();
    {   // store: thread (h, j0): 32 B contiguous; wave covers 2 KB contiguous
        const int h  = t >> 1;
        const int j0 = (t & 1) << 4;    // k = j0..j0+15
        union { bf16x8 v[2]; __bf16 e[16]; } ob;
        #pragma unroll
        for (int q = 0; q < 16; ++q) ob.e[q] = tile[j0 + q][h];
        __bf16* dst = T + ((size_t)b * 16 + blockIdx.x) * 4096 + h * 32 + j0;
        *(bf16x8*)(dst + 0) = ob.v[0];
        *(bf16x8*)(dst + 8) = ob.v[1];
    }
}

// ---------- coalesced gather/relu/mask_j -> blocked bf16 W + global max ------
__global__ __launch_bounds__(256) void k_prepack(const int* __restrict__ cog,
                                                 const int* __restrict__ rmat,
                                                 const float* __restrict__ dmat,
                                                 const float* __restrict__ mask,
                                                 const float* __restrict__ domain,
                                                 __bf16* __restrict__ W,
                                                 unsigned int* __restrict__ gmax) {
    __shared__ float sdom[NCOG * NRB];   // 20736 B
    __shared__ float smask[N_];          // 2048 B
    __shared__ float swmax[4];
    const int b  = blockIdx.y;
    const int i0 = blockIdx.x * 16;      // 16-row group
    const int t  = threadIdx.x;
    for (int k = t; k < NCOG * NRB; k += 256) sdom[k] = domain[k];
    for (int k = t; k < N_; k += 256) smask[k] = mask[b * N_ + k];
    __syncthreads();

    const size_t base = ((size_t)b * N_ + i0) * N_;
    float wmax = 0.0f;

    #pragma unroll
    for (int p = 0; p < 4; ++p) {        // 16 rows x 512 j in 4 passes
        const int e  = p * 2048 + t * 8; // 8 consecutive j per thread
        const int rl = e >> 9;           // local row 0..15
        const int j  = e & 511;
        const size_t off = base + (size_t)rl * N_ + j;
        union { int4 v[2]; int   e8[8]; } ci, ri;
        union { int4 v[2]; float f[8]; } di;
        ci.v[0] = *(const int4*)(cog + off);   ci.v[1] = *(const int4*)(cog + off + 4);
        ri.v[0] = *(const int4*)(rmat + off);  ri.v[1] = *(const int4*)(rmat + off + 4);
        di.v[0] = *(const int4*)((const int*)dmat + off);
        di.v[1] = *(const int4*)((const int*)dmat + off + 4);

        union { bf16x8 v8; __bf16 h[8]; } wv;
        float lmax = 0.0f;
        #pragma unroll
        for (int q = 0; q < 8; ++q) {
            float val = sdom[ci.e8[q] * NRB + ri.e8[q]] - di.f[q];
            val = fmaxf(val, 0.0f) * smask[j + q];
            lmax = fmaxf(lmax, val);
            wv.h[q] = (__bf16)val;
        }
        wmax = fmaxf(wmax, lmax * smask[i0 + rl]);   // fold m_i into the max

        const int i = i0 + rl;
        __bf16* dst = W + ((size_t)(b * 4 + (i >> 7)) * 16 + (j >> 5)) * 4096
                        + (i & 127) * 32 + (j & 31);
        *(bf16x8*)dst = wv.v8;
    }

    #pragma unroll
    for (int off = 32; off > 0; off >>= 1)
        wmax = fmaxf(wmax, __shfl_down(wmax, off));
    if ((t & 63) == 0) swmax[t >> 6] = wmax;
    __syncthreads();
    if (t == 0) {
        float m = fmaxf(fmaxf(swmax[0], swmax[1]), fmaxf(swmax[2], swmax[3]));
        atomicMax(gmax, __float_as_uint(m));   // floats >= 0: uint cmp == float cmp
    }
}

// ---------- pure GEMM: no LDS, no barriers, 1KB-contiguous wave loads -------
__global__ __launch_bounds__(512, 1) void k_gemm(const __bf16* __restrict__ W,
                                                 const __bf16* __restrict__ T,
                                                 float* __restrict__ out) {
    const int id = blockIdx.x;
    const int b  = (id & 7) + 8 * (id >> 5);   // same-b blocks share an XCD
    const int it = (id >> 3) & 3;
    const int t = threadIdx.x, wave = t >> 6, lane = t & 63;
    const int quad = lane >> 4, lrow = lane & 15;

    const __bf16* Ab = W + (size_t)(b * 4 + it) * 16 * 4096
                         + (wave * 16 + lrow) * 32 + quad * 8;
    const __bf16* Bb = T + (size_t)b * 16 * 4096 + lrow * 32 + quad * 8;

    union U { int4 i; bf16x8 h; };
    U av, bv0, bv1, bv2, bv3, bv4, bv5, bv6, bv7;   // parity 0
    U au, bu0, bu1, bu2, bu3, bu4, bu5, bu6, bu7;   // parity 1

    f32x4 acc[8];
    #pragma unroll
    for (int i = 0; i < 8; ++i) acc[i] = (f32x4)0.0f;

    #define GLD(s, A, B0,B1,B2,B3,B4,B5,B6,B7) do {        \
        const __bf16* ap = Ab + (s) * 4096;                 \
        const __bf16* bp = Bb + (s) * 4096;                 \
        A.i  = *(const int4*)ap;                            \
        B0.i = *(const int4*)(bp + 0 * 512);                \
        B1.i = *(const int4*)(bp + 1 * 512);                \
        B2.i = *(const int4*)(bp + 2 * 512);                \
        B3.i = *(const int4*)(bp + 3 * 512);                \
        B4.i = *(const int4*)(bp + 4 * 512);                \
        B5.i = *(const int4*)(bp + 5 * 512);                \
        B6.i = *(const int4*)(bp + 6 * 512);                \
        B7.i = *(const int4*)(bp + 7 * 512); } while (0)

    #define COMP(A, B0,B1,B2,B3,B4,B5,B6,B7) do {                               \
        acc[0] = __builtin_amdgcn_mfma_f32_16x16x32_bf16(A.h, B0.h, acc[0], 0, 0, 0); \
        acc[1] = __builtin_amdgcn_mfma_f32_16x16x32_bf16(A.h, B1.h, acc[1], 0, 0, 0); \
        acc[2] = __builtin_amdgcn_mfma_f32_16x16x32_bf16(A.h, B2.h, acc[2], 0, 0, 0); \
        acc[3] = __builtin_amdgcn_mfma_f32_16x16x32_bf16(A.h, B3.h, acc[3], 0, 0, 0); \
        acc[4] = __builtin_amdgcn_mfma_f32_16x16x32_bf16(A.h, B4.h, acc[4], 0, 0, 0); \
        acc[5] = __builtin_amdgcn_mfma_f32_16x16x32_bf16(A.h, B5.h, acc[5], 0, 0, 0); \
        acc[6] = __builtin_amdgcn_mfma_f32_16x16x32_bf16(A.h, B6.h, acc[6], 0, 0, 0); \
        acc[7] = __builtin_amdgcn_mfma_f32_16x16x32_bf16(A.h, B7.h, acc[7], 0, 0, 0); \
    } while (0)

    GLD(0, av, bv0, bv1, bv2, bv3, bv4, bv5, bv6, bv7);
    GLD(1, au, bu0, bu1, bu2, bu3, bu4, bu5, bu6, bu7);
    for (int sp = 0; sp < 8; ++sp) {
        const int s0 = sp * 2;
        COMP(av, bv0, bv1, bv2, bv3, bv4, bv5, bv6, bv7);
        if (s0 + 2 < 16) GLD(s0 + 2, av, bv0, bv1, bv2, bv3, bv4, bv5, bv6, bv7);
        COMP(au, bu0, bu1, bu2, bu3, bu4, bu5, bu6, bu7);
        if (s0 + 3 < 16) GLD(s0 + 3, au, bu0, bu1, bu2, bu3, bu4, bu5, bu6, bu7);
    }
    #undef GLD
    #undef COMP

    // unnormalized output; D layout: col=lane&15, row=quad*4+reg
    const int orow0 = it * 128 + wave * 16 + quad * 4;
    #pragma unroll
    for (int nt = 0; nt < 8; ++nt) {
        #pragma unroll
        for (int r = 0; r < 4; ++r)
            out[((size_t)b * N_ + orow0 + r) * H_ + nt * 16 + lrow] = acc[nt][r];
    }
}

// ---------- scale by m_i / gmax ----------
__global__ __launch_bounds__(256) void k_scale(float* __restrict__ out,
                                               const float* __restrict__ mask,
                                               const unsigned int* __restrict__ gmax) {
    const float inv = 1.0f / __uint_as_float(*gmax);
    const int idx = blockIdx.x * 256 + threadIdx.x;     // 1,048,576 float4s
    const float m = mask[idx >> 5] * inv;               // 32 float4 per (b,i) row
    float4* p = (float4*)out;
    float4 v = p[idx];
    v.x *= m; v.y *= m; v.z *= m; v.w *= m;
    p[idx] = v;
}

extern "C" void kernel_launch(void* const* d_in, const int* in_sizes, int n_in,
                              void* d_out, int out_size, void* d_ws, size_t ws_size,
                              hipStream_t stream) {
    const float* ht     = (const float*)d_in[0];   // (N,B,H) f32
    const int*   rmat   = (const int*)  d_in[1];   // (B,N,N) i32
    const float* dmat   = (const float*)d_in[2];   // (B,N,N) f32
    const float* mask   = (const float*)d_in[3];   // (B,N)   f32
    const int*   cog    = (const int*)  d_in[4];   // (B,N,N) i32
    const float* domain = (const float*)d_in[5];   // (72,72) f32
    float* out = (float*)d_out;

    unsigned int* gmax = (unsigned int*)d_ws;
    __bf16* T = (__bf16*)((char*)d_ws + 256);                  // 8 MiB blocked T
    __bf16* W = (__bf16*)((char*)d_ws + 256 + 8 * 1024 * 1024); // 32 MiB blocked W

    hipMemsetAsync(d_ws, 0, 256, stream);          // gmax = 0.0f
    k_transpose<<<dim3(16, 64), 256, 0, stream>>>(ht, T);
    k_prepack<<<dim3(32, 64), 256, 0, stream>>>(cog, rmat, dmat, mask, domain, W, gmax);
    k_gemm<<<dim3(256), 512, 0, stream>>>(W, T, out);
    k_scale<<<4096, 256, 0, stream>>>(out, mask, gmax);
}

// Round 10
// 252.949 us; speedup vs baseline: 1.0086x; 1.0086x over previous
//
#include <hip/hip_runtime.h>

// hardwiredAttention: out[b,i,h] = sum_j w[b,i,j] * h_t[j,b,h]
//   w = m_i*m_j*relu(domain[cog,r]-d) / max(w)
// R10 = R9 with k_prepack software-pipelined via NAMED staging registers.
// R9's prepack compiled to VGPR_Count=36 -> fully serialized passes (same
// 86us even with L3-resident inputs = latency-bound, not BW-bound). Now:
// depth-2 register pipeline (ISSUE p+1 / COMPUTE p), no barriers in loop,
// wave w owns row i0+4p+w, lanes own 8 consecutive j -> coalesced 2KB/wave.

#define B_   64
#define N_   512
#define H_   128
#define NCOG 72
#define NRB  72

typedef __bf16 bf16x8 __attribute__((ext_vector_type(8)));
typedef float  f32x4  __attribute__((ext_vector_type(4)));

// ---------- h_t[j][b][h] fp32 -> T_blk[b][s][h][k] bf16 (s=j>>5, k=j&31) ----
__global__ __launch_bounds__(256) void k_transpose(const float* __restrict__ ht,
                                                   __bf16* __restrict__ T) {
    __shared__ __bf16 tile[32][136];
    const int jt = blockIdx.x * 32;     // j-tile == slab s = blockIdx.x
    const int b  = blockIdx.y;
    const int t  = threadIdx.x;
    {   // load 32 j-rows x 128 h, coalesced on h
        const int jj = t >> 3;
        const int h0 = (t & 7) << 4;
        const float* src = ht + ((size_t)(jt + jj) * B_ + b) * H_ + h0;
        float4 v0 = *(const float4*)(src + 0);
        float4 v1 = *(const float4*)(src + 4);
        float4 v2 = *(const float4*)(src + 8);
        float4 v3 = *(const float4*)(src + 12);
        __bf16* dst = &tile[jj][h0];
        dst[0]=(__bf16)v0.x; dst[1]=(__bf16)v0.y; dst[2]=(__bf16)v0.z; dst[3]=(__bf16)v0.w;
        dst[4]=(__bf16)v1.x; dst[5]=(__bf16)v1.y; dst[6]=(__bf16)v1.z; dst[7]=(__bf16)v1.w;
        dst[8]=(__bf16)v2.x; dst[9]=(__bf16)v2.y; dst[10]=(__bf16)v2.z; dst[11]=(__bf16)v2.w;
        dst[12]=(__bf16)v3.x; dst[13]=(__bf16)v3.y; dst[14]=(__bf16)v3.z; dst[15]=(__bf16)v3.w;
    }
    __syncthreads();
    {   // store: thread (h, j0): 32 B contiguous; wave covers 2 KB contiguous
        const int h  = t >> 1;
        const int j0 = (t & 1) << 4;    // k = j0..j0+15
        union { bf16x8 v[2]; __bf16 e[16]; } ob;
        #pragma unroll
        for (int q = 0; q < 16; ++q) ob.e[q] = tile[j0 + q][h];
        __bf16* dst = T + ((size_t)b * 16 + blockIdx.x) * 4096 + h * 32 + j0;
        *(bf16x8*)(dst + 0) = ob.v[0];
        *(bf16x8*)(dst + 8) = ob.v[1];
    }
}

// ---------- coalesced gather/relu/mask_j -> blocked bf16 W + global max ------
// wave w, pass p: row i0+4p+w; lane: j = lane*8 (8 consecutive). Depth-2
// register pipeline with named int4 regs (no arrays -> no scratch).
__global__ __launch_bounds__(256, 4) void k_prepack(const int* __restrict__ cog,
                                                    const int* __restrict__ rmat,
                                                    const float* __restrict__ dmat,
                                                    const float* __restrict__ mask,
                                                    const float* __restrict__ domain,
                                                    __bf16* __restrict__ W,
                                                    unsigned int* __restrict__ gmax) {
    __shared__ float sdom[NCOG * NRB];   // 20736 B
    __shared__ float smask[N_];          // 2048 B
    __shared__ float swmax[4];
    const int b  = blockIdx.y;
    const int i0 = blockIdx.x * 16;      // 16-row group
    const int t  = threadIdx.x;
    const int wave = t >> 6, lane = t & 63;
    for (int k = t; k < NCOG * NRB; k += 256) sdom[k] = domain[k];
    for (int k = t; k < N_; k += 256) smask[k] = mask[b * N_ + k];
    __syncthreads();

    const int j = lane * 8;
    const size_t base = ((size_t)b * N_ + i0 + wave) * N_ + j;   // pass p: + 4p*N_
    // W dst: i = i0+4p+wave, slab = j>>5 = lane>>2, k = j&31 = (lane&3)*8
    __bf16* wbase = W + ((size_t)(b * 4 + (i0 >> 7)) * 16 + (lane >> 2)) * 4096
                      + ((i0 & 127) + wave) * 32 + (lane & 3) * 8;  // pass p: + 4p*32

    int4 a0, a1, a2, a3, a4, a5;   // parity-0 staging
    int4 b0, b1, b2, b3, b4, b5;   // parity-1 staging
    float wmax = 0.0f;

    #define PISSUE(p, R0,R1,R2,R3,R4,R5) do {                 \
        const size_t off = base + (size_t)((p) * 4) * N_;      \
        R0 = *(const int4*)(cog + off);                        \
        R1 = *(const int4*)(cog + off + 4);                    \
        R2 = *(const int4*)(rmat + off);                       \
        R3 = *(const int4*)(rmat + off + 4);                   \
        R4 = *(const int4*)((const int*)dmat + off);           \
        R5 = *(const int4*)((const int*)dmat + off + 4); } while (0)

    #define PCOMP(p, R0,R1,R2,R3,R4,R5) do {                   \
        union { int4 v[2]; int   e8[8]; } ci, ri;              \
        union { int4 v[2]; float f[8]; } di;                   \
        ci.v[0] = R0; ci.v[1] = R1;                            \
        ri.v[0] = R2; ri.v[1] = R3;                            \
        di.v[0] = R4; di.v[1] = R5;                            \
        union { bf16x8 v8; __bf16 h[8]; } wv;                  \
        float lmax = 0.0f;                                     \
        _Pragma("unroll")                                      \
        for (int q = 0; q < 8; ++q) {                          \
            float val = sdom[ci.e8[q] * NRB + ri.e8[q]] - di.f[q]; \
            val = fmaxf(val, 0.0f) * smask[j + q];             \
            lmax = fmaxf(lmax, val);                           \
            wv.h[q] = (__bf16)val;                             \
        }                                                      \
        wmax = fmaxf(wmax, lmax * smask[i0 + (p) * 4 + wave]); \
        *(bf16x8*)(wbase + (p) * 4 * 32) = wv.v8; } while (0)

    PISSUE(0, a0, a1, a2, a3, a4, a5);
    PISSUE(1, b0, b1, b2, b3, b4, b5);
    PCOMP(0, a0, a1, a2, a3, a4, a5);
    PISSUE(2, a0, a1, a2, a3, a4, a5);
    PCOMP(1, b0, b1, b2, b3, b4, b5);
    PISSUE(3, b0, b1, b2, b3, b4, b5);
    PCOMP(2, a0, a1, a2, a3, a4, a5);
    PCOMP(3, b0, b1, b2, b3, b4, b5);
    #undef PISSUE
    #undef PCOMP

    #pragma unroll
    for (int off = 32; off > 0; off >>= 1)
        wmax = fmaxf(wmax, __shfl_down(wmax, off));
    if (lane == 0) swmax[wave] = wmax;
    __syncthreads();
    if (t == 0) {
        float m = fmaxf(fmaxf(swmax[0], swmax[1]), fmaxf(swmax[2], swmax[3]));
        atomicMax(gmax, __float_as_uint(m));   // floats >= 0: uint cmp == float cmp
    }
}

// ---------- pure GEMM: no LDS, no barriers, 1KB-contiguous wave loads -------
__global__ __launch_bounds__(512, 1) void k_gemm(const __bf16* __restrict__ W,
                                                 const __bf16* __restrict__ T,
                                                 float* __restrict__ out) {
    const int id = blockIdx.x;
    const int b  = (id & 7) + 8 * (id >> 5);   // same-b blocks share an XCD
    const int it = (id >> 3) & 3;
    const int t = threadIdx.x, wave = t >> 6, lane = t & 63;
    const int quad = lane >> 4, lrow = lane & 15;

    const __bf16* Ab = W + (size_t)(b * 4 + it) * 16 * 4096
                         + (wave * 16 + lrow) * 32 + quad * 8;
    const __bf16* Bb = T + (size_t)b * 16 * 4096 + lrow * 32 + quad * 8;

    union U { int4 i; bf16x8 h; };
    U av, bv0, bv1, bv2, bv3, bv4, bv5, bv6, bv7;   // parity 0
    U au, bu0, bu1, bu2, bu3, bu4, bu5, bu6, bu7;   // parity 1

    f32x4 acc[8];
    #pragma unroll
    for (int i = 0; i < 8; ++i) acc[i] = (f32x4)0.0f;

    #define GLD(s, A, B0,B1,B2,B3,B4,B5,B6,B7) do {        \
        const __bf16* ap = Ab + (s) * 4096;                 \
        const __bf16* bp = Bb + (s) * 4096;                 \
        A.i  = *(const int4*)ap;                            \
        B0.i = *(const int4*)(bp + 0 * 512);                \
        B1.i = *(const int4*)(bp + 1 * 512);                \
        B2.i = *(const int4*)(bp + 2 * 512);                \
        B3.i = *(const int4*)(bp + 3 * 512);                \
        B4.i = *(const int4*)(bp + 4 * 512);                \
        B5.i = *(const int4*)(bp + 5 * 512);                \
        B6.i = *(const int4*)(bp + 6 * 512);                \
        B7.i = *(const int4*)(bp + 7 * 512); } while (0)

    #define COMP(A, B0,B1,B2,B3,B4,B5,B6,B7) do {                               \
        acc[0] = __builtin_amdgcn_mfma_f32_16x16x32_bf16(A.h, B0.h, acc[0], 0, 0, 0); \
        acc[1] = __builtin_amdgcn_mfma_f32_16x16x32_bf16(A.h, B1.h, acc[1], 0, 0, 0); \
        acc[2] = __builtin_amdgcn_mfma_f32_16x16x32_bf16(A.h, B2.h, acc[2], 0, 0, 0); \
        acc[3] = __builtin_amdgcn_mfma_f32_16x16x32_bf16(A.h, B3.h, acc[3], 0, 0, 0); \
        acc[4] = __builtin_amdgcn_mfma_f32_16x16x32_bf16(A.h, B4.h, acc[4], 0, 0, 0); \
        acc[5] = __builtin_amdgcn_mfma_f32_16x16x32_bf16(A.h, B5.h, acc[5], 0, 0, 0); \
        acc[6] = __builtin_amdgcn_mfma_f32_16x16x32_bf16(A.h, B6.h, acc[6], 0, 0, 0); \
        acc[7] = __builtin_amdgcn_mfma_f32_16x16x32_bf16(A.h, B7.h, acc[7], 0, 0, 0); \
    } while (0)

    GLD(0, av, bv0, bv1, bv2, bv3, bv4, bv5, bv6, bv7);
    GLD(1, au, bu0, bu1, bu2, bu3, bu4, bu5, bu6, bu7);
    for (int sp = 0; sp < 8; ++sp) {
        const int s0 = sp * 2;
        COMP(av, bv0, bv1, bv2, bv3, bv4, bv5, bv6, bv7);
        if (s0 + 2 < 16) GLD(s0 + 2, av, bv0, bv1, bv2, bv3, bv4, bv5, bv6, bv7);
        COMP(au, bu0, bu1, bu2, bu3, bu4, bu5, bu6, bu7);
        if (s0 + 3 < 16) GLD(s0 + 3, au, bu0, bu1, bu2, bu3, bu4, bu5, bu6, bu7);
    }
    #undef GLD
    #undef COMP

    // unnormalized output; D layout: col=lane&15, row=quad*4+reg
    const int orow0 = it * 128 + wave * 16 + quad * 4;
    #pragma unroll
    for (int nt = 0; nt < 8; ++nt) {
        #pragma unroll
        for (int r = 0; r < 4; ++r)
            out[((size_t)b * N_ + orow0 + r) * H_ + nt * 16 + lrow] = acc[nt][r];
    }
}

// ---------- scale by m_i / gmax ----------
__global__ __launch_bounds__(256) void k_scale(float* __restrict__ out,
                                               const float* __restrict__ mask,
                                               const unsigned int* __restrict__ gmax) {
    const float inv = 1.0f / __uint_as_float(*gmax);
    const int idx = blockIdx.x * 256 + threadIdx.x;     // 1,048,576 float4s
    const float m = mask[idx >> 5] * inv;               // 32 float4 per (b,i) row
    float4* p = (float4*)out;
    float4 v = p[idx];
    v.x *= m; v.y *= m; v.z *= m; v.w *= m;
    p[idx] = v;
}

extern "C" void kernel_launch(void* const* d_in, const int* in_sizes, int n_in,
                              void* d_out, int out_size, void* d_ws, size_t ws_size,
                              hipStream_t stream) {
    const float* ht     = (const float*)d_in[0];   // (N,B,H) f32
    const int*   rmat   = (const int*)  d_in[1];   // (B,N,N) i32
    const float* dmat   = (const float*)d_in[2];   // (B,N,N) f32
    const float* mask   = (const float*)d_in[3];   // (B,N)   f32
    const int*   cog    = (const int*)  d_in[4];   // (B,N,N) i32
    const float* domain = (const float*)d_in[5];   // (72,72) f32
    float* out = (float*)d_out;

    unsigned int* gmax = (unsigned int*)d_ws;
    __bf16* T = (__bf16*)((char*)d_ws + 256);                  // 8 MiB blocked T
    __bf16* W = (__bf16*)((char*)d_ws + 256 + 8 * 1024 * 1024); // 32 MiB blocked W

    hipMemsetAsync(d_ws, 0, 256, stream);          // gmax = 0.0f
    k_transpose<<<dim3(16, 64), 256, 0, stream>>>(ht, T);
    k_prepack<<<dim3(32, 64), 256, 0, stream>>>(cog, rmat, dmat, mask, domain, W, gmax);
    k_gemm<<<dim3(256), 512, 0, stream>>>(W, T, out);
    k_scale<<<4096, 256, 0, stream>>>(out, mask, gmax);
}